// Round 1
// 754.857 us; speedup vs baseline: 1.5776x; 1.5776x over previous
//
#include <hip/hip_runtime.h>
#include <hip/hip_fp16.h>
#include <math.h>

// ---------------------------------------------------------------------------
// MultiResImplicitFeature round 3.
// R2 post-mortem: VGPR=40 proves the compiler serialized the gathers
// (~2.3 loads in flight/wave by Little's law); WRITE_SIZE=2.84x ideal from
// partial-line per-lane float4 NT stores. Changes:
//   * 64-thread blocks, __launch_bounds__(64,2): 256-VGPR budget so ALL 32
//     gathers (4 grids x 8 corners, dwordx4 each) are issued before any use.
//   * reduce in issue order (g3 first) so vmcnt waits are shortest-first.
//   * output staged in LDS (64 rows x 57-float stride: conflict-free), then
//     written as 56 fully-coalesced 256B-per-instr NT store bursts ->
//     WRITE_SIZE drops to the 448MB ideal, no write-allocate fills.
//   * 4 transpose launches fused into 1.
// ---------------------------------------------------------------------------

typedef float f32x4 __attribute__((ext_vector_type(4)));

// voxel counts: 16^3=4096, 32^3=32768, 64^3=262144, 128^3=2097152
#define V0 4096
#define V1 32768
#define V2 262144
#define V3 2097152
#define CUM1 (V0)
#define CUM2 (V0 + V1)
#define CUM3 (V0 + V1 + V2)
#define CUMT (V0 + V1 + V2 + V3)

__global__ __launch_bounds__(256) void transpose_grids_h(
    const float* __restrict__ g0, const float* __restrict__ g1,
    const float* __restrict__ g2, const float* __restrict__ g3,
    __half* __restrict__ ws)
{
    int v = blockIdx.x * 256 + threadIdx.x;
    if (v >= CUMT) return;
    const float* g;
    int local, R3;
    size_t off;  // in half-elements
    if (v < CUM1)      { g = g0; local = v;        R3 = V0; off = 0; }
    else if (v < CUM2) { g = g1; local = v - CUM1; R3 = V1; off = (size_t)CUM1 * 8; }
    else if (v < CUM3) { g = g2; local = v - CUM2; R3 = V2; off = (size_t)CUM2 * 8; }
    else               { g = g3; local = v - CUM3; R3 = V3; off = (size_t)CUM3 * 8; }
    union { __half h[8]; f32x4 f; } u;
#pragma unroll
    for (int c = 0; c < 8; ++c) u.h[c] = __float2half(g[(size_t)c * R3 + local]);
    *reinterpret_cast<f32x4*>(ws + off + (size_t)local * 8) = u.f;
}

template <int R>
__device__ __forceinline__ void gather8_issue(const __half* __restrict__ g,
                                              float px, float py, float pz,
                                              f32x4 d[8],
                                              float& wx, float& wy, float& wz)
{
    const float rm1 = (float)(R - 1);
    float cx = (px + 1.0f) * 0.5f * rm1;
    float cy = (py + 1.0f) * 0.5f * rm1;
    float cz = (pz + 1.0f) * 0.5f * rm1;
    float fx = floorf(cx), fy = floorf(cy), fz = floorf(cz);
    wx = cx - fx; wy = cy - fy; wz = cz - fz;
    int x0 = min(max((int)fx, 0), R - 1);
    int y0 = min(max((int)fy, 0), R - 1);
    int z0 = min(max((int)fz, 0), R - 1);
    int x1 = min(x0 + 1, R - 1);
    int y1 = min(y0 + 1, R - 1);
    int z1 = min(z0 + 1, R - 1);

    int r00 = (z0 * R + y0) * R;
    int r01 = (z0 * R + y1) * R;
    int r10 = (z1 * R + y0) * R;
    int r11 = (z1 * R + y1) * R;

    // corner order: (dz,dy,dx) = 000,001,010,011,100,101,110,111
    int idx[8] = {r00 + x0, r00 + x1, r01 + x0, r01 + x1,
                  r10 + x0, r10 + x1, r11 + x0, r11 + x1};
#pragma unroll
    for (int k = 0; k < 8; ++k)
        d[k] = *reinterpret_cast<const f32x4*>(g + ((size_t)idx[k] << 3));
}

__device__ __forceinline__ void reduce8w(const f32x4 d[8],
                                         float wx, float wy, float wz,
                                         float* __restrict__ o)
{
    float vx = 1.0f - wx, vy = 1.0f - wy, vz = 1.0f - wz;
    float w[8];
    w[0] = vz * vy * vx; w[1] = vz * vy * wx;
    w[2] = vz * wy * vx; w[3] = vz * wy * wx;
    w[4] = wz * vy * vx; w[5] = wz * vy * wx;
    w[6] = wz * wy * vx; w[7] = wz * wy * wx;
    float acc[8];
#pragma unroll
    for (int c = 0; c < 8; ++c) acc[c] = 0.0f;
#pragma unroll
    for (int k = 0; k < 8; ++k) {
        union { f32x4 f; __half2 h2[4]; } u;
        u.f = d[k];
        float wk = w[k];
        float2 p0 = __half22float2(u.h2[0]);
        float2 p1 = __half22float2(u.h2[1]);
        float2 p2 = __half22float2(u.h2[2]);
        float2 p3 = __half22float2(u.h2[3]);
        acc[0] += wk * p0.x; acc[1] += wk * p0.y;
        acc[2] += wk * p1.x; acc[3] += wk * p1.y;
        acc[4] += wk * p2.x; acc[5] += wk * p2.y;
        acc[6] += wk * p3.x; acc[7] += wk * p3.y;
    }
#pragma unroll
    for (int c = 0; c < 8; ++c) o[c] = acc[c];
}

__global__ __launch_bounds__(64, 2) void mrif_h_kernel(
    const float* __restrict__ x,
    const __half* __restrict__ g0, const __half* __restrict__ g1,
    const __half* __restrict__ g2, const __half* __restrict__ g3,
    float* __restrict__ out, int n)
{
    // 64 rows x 57-float stride: write bank = (25*lane + c) % 32 -> bijective
    // over 32 lanes (2-way over 64 = free); read addr = q + q/56 -> 2-way max.
    __shared__ float lrow[64 * 57];
    const int lane = threadIdx.x;
    int i = blockIdx.x * 64 + lane;
    int ii = min(i, n - 1);  // clamp; no early return (barrier below)

    float px = x[3 * ii + 0];
    float py = x[3 * ii + 1];
    float pz = x[3 * ii + 2];

    // ---- issue ALL 32 gathers before any consumption: 128 VGPRs in flight ----
    f32x4 d3[8], d2[8], d1[8], d0[8];
    float w3x, w3y, w3z, w2x, w2y, w2z, w1x, w1y, w1z, w0x, w0y, w0z;
    gather8_issue<128>(g3, px, py, pz, d3, w3x, w3y, w3z);
    gather8_issue<64> (g2, px, py, pz, d2, w2x, w2y, w2z);
    gather8_issue<32> (g1, px, py, pz, d1, w1x, w1y, w1z);
    gather8_issue<16> (g0, px, py, pz, d0, w0x, w0y, w0z);

    // ---- VALU work overlaps the in-flight gathers; results go to LDS ----
    float* row = lrow + lane * 57;
    const float HPI = 1.57079632679489662f;
#pragma unroll
    for (int l = 0; l < 4; ++l) {
        float coef = HPI * (float)(l + 1);
        float s, c;
        __sincosf(coef * px, &s, &c); row[l * 3 + 0] = s; row[12 + l * 3 + 0] = c;
        __sincosf(coef * py, &s, &c); row[l * 3 + 1] = s; row[12 + l * 3 + 1] = c;
        __sincosf(coef * pz, &s, &c); row[l * 3 + 2] = s; row[12 + l * 3 + 2] = c;
    }

    // ---- reduce in issue order (shortest vmcnt wait first) ----
    reduce8w(d3, w3x, w3y, w3z, row + 48);
    reduce8w(d2, w2x, w2y, w2z, row + 40);
    reduce8w(d1, w1x, w1y, w1z, row + 32);
    reduce8w(d0, w0x, w0y, w0z, row + 24);

    __syncthreads();

    // ---- coalesced write-out: 56 bursts of 64 lanes x 4B = 256B contiguous ----
    const size_t base = (size_t)blockIdx.x * (64 * 56);
    const size_t nwords = (size_t)n * 56;
#pragma unroll
    for (int k = 0; k < 56; ++k) {
        int q = k * 64 + lane;     // word index within this wave's 14336B chunk
        int r = q / 56;            // compiler emits magic-mul
        int c = q - r * 56;
        size_t w = base + (size_t)q;
        if (w < nwords)
            __builtin_nontemporal_store(lrow[r * 57 + c], out + w);
    }
}

// Fallback (ws too small): gather fp32 channel-first directly.
__global__ __launch_bounds__(256) void mrif_fallback_kernel(
    const float* __restrict__ x,
    const float* __restrict__ g0, const float* __restrict__ g1,
    const float* __restrict__ g2, const float* __restrict__ g3,
    float* __restrict__ out, int n)
{
    int i = blockIdx.x * 256 + threadIdx.x;
    if (i >= n) return;
    float px = x[3 * i + 0], py = x[3 * i + 1], pz = x[3 * i + 2];
    float* orow = out + (size_t)i * 56;

    const float HPI = 1.57079632679489662f;
#pragma unroll
    for (int l = 0; l < 4; ++l) {
        float coef = HPI * (float)(l + 1);
        __sincosf(coef * px, &orow[l * 3 + 0], &orow[12 + l * 3 + 0]);
        __sincosf(coef * py, &orow[l * 3 + 1], &orow[12 + l * 3 + 1]);
        __sincosf(coef * pz, &orow[l * 3 + 2], &orow[12 + l * 3 + 2]);
    }
    const float* gs[4] = {g0, g1, g2, g3};
    const int Rs[4] = {16, 32, 64, 128};
    for (int gi = 0; gi < 4; ++gi) {
        const float* g = gs[gi];
        int R = Rs[gi];
        const float rm1 = (float)(R - 1);
        float cx = (px + 1.0f) * 0.5f * rm1;
        float cy = (py + 1.0f) * 0.5f * rm1;
        float cz = (pz + 1.0f) * 0.5f * rm1;
        float fx = floorf(cx), fy = floorf(cy), fz = floorf(cz);
        float wx = cx - fx, wy = cy - fy, wz = cz - fz;
        int x0 = min(max((int)fx, 0), R - 1);
        int y0 = min(max((int)fy, 0), R - 1);
        int z0 = min(max((int)fz, 0), R - 1);
        int x1 = min(x0 + 1, R - 1), y1 = min(y0 + 1, R - 1), z1 = min(z0 + 1, R - 1);
        size_t R3 = (size_t)R * R * R;
        float wxa[2] = {1.0f - wx, wx}, wya[2] = {1.0f - wy, wy}, wza[2] = {1.0f - wz, wz};
        int xi[2] = {x0, x1}, yi[2] = {y0, y1}, zi[2] = {z0, z1};
        float acc[8];
        for (int c = 0; c < 8; ++c) acc[c] = 0.0f;
        for (int dz = 0; dz < 2; ++dz)
            for (int dy = 0; dy < 2; ++dy)
                for (int dx = 0; dx < 2; ++dx) {
                    float w = wza[dz] * wya[dy] * wxa[dx];
                    size_t base = ((size_t)zi[dz] * R + yi[dy]) * R + xi[dx];
                    for (int c = 0; c < 8; ++c) acc[c] += w * g[c * R3 + base];
                }
        for (int c = 0; c < 8; ++c) orow[24 + gi * 8 + c] = acc[c];
    }
}

extern "C" void kernel_launch(void* const* d_in, const int* in_sizes, int n_in,
                              void* d_out, int out_size, void* d_ws, size_t ws_size,
                              hipStream_t stream)
{
    const float* x = (const float*)d_in[0];
    const float* g[4] = {(const float*)d_in[1], (const float*)d_in[2],
                         (const float*)d_in[3], (const float*)d_in[4]};

    float* out = (float*)d_out;
    const int n = in_sizes[0] / 3;

    const size_t total_halves = (size_t)CUMT * 8;

    if (ws_size >= total_halves * sizeof(__half)) {
        __half* wsh = (__half*)d_ws;
        transpose_grids_h<<<(CUMT + 255) / 256, 256, 0, stream>>>(
            g[0], g[1], g[2], g[3], wsh);
        const int blocks = (n + 63) / 64;
        mrif_h_kernel<<<blocks, 64, 0, stream>>>(
            x,
            wsh,
            wsh + (size_t)CUM1 * 8,
            wsh + (size_t)CUM2 * 8,
            wsh + (size_t)CUM3 * 8,
            out, n);
    } else {
        const int threads = 256;
        const int blocks = (n + threads - 1) / threads;
        mrif_fallback_kernel<<<blocks, threads, 0, stream>>>(
            x, g[0], g[1], g[2], g[3], out, n);
    }
}